// Round 1
// baseline (961.255 us; speedup 1.0000x reference)
//
#include <hip/hip_runtime.h>
#include <math.h>

#define NTHR 512
#define BT 16

__device__ __forceinline__ float sigf(float x) { return 1.0f / (1.0f + __expf(-x)); }
__device__ __forceinline__ float tanhfast(float x) { return 2.0f / (1.0f + __expf(-2.0f * x)) - 1.0f; }

__global__ void wsum_kernel(const float* __restrict__ wk, const float* __restrict__ wr,
                            float* __restrict__ ws) {
  int i = blockIdx.x * blockDim.x + threadIdx.x;
  if (i < 128 * 512) ws[i] = wk[i] + wr[i];
}

template <bool USE_WSUM>
__global__ __launch_bounds__(NTHR, 1) void ed_kernel(
    const float* __restrict__ a, const float* __restrict__ b,
    const float* __restrict__ W_combine, const float* __restrict__ b_combine,
    const float* __restrict__ W_first, const float* __restrict__ b_first,
    const float* __restrict__ Wk_enc, const float* __restrict__ Wr_enc,
    const float* __restrict__ bias_enc, const float* __restrict__ Wk_dec,
    const float* __restrict__ Wr_dec, const float* __restrict__ bias_dec,
    const float* __restrict__ W_out, const float* __restrict__ b_out,
    const float* __restrict__ Wsum, float* __restrict__ out) {
  // u_t: transposed input+state buffer u_t[k][r].
  // Encoder: k 0..63 = x_t, k 64..191 = h.  Decoder step1: k 0..127 = x0, 128..255 = h_enc.
  // Decoder steps 2+: k 0..127 = h (input == hidden, use Wsum).
  __shared__ __align__(16) float u_t[256][BT];     // 16 KB
  __shared__ __align__(16) float zbuf[BT][512];    // 32 KB
  __shared__ __align__(16) float cst[BT][128];     // 8 KB
  __shared__ __align__(16) float sWc[16 * 64];     // 4 KB
  __shared__ float sbias_e[512];
  __shared__ float sbias_d[512];
  __shared__ float sWout[128];
  __shared__ float sbcomb[64];
  __shared__ float sbfirst[128];
  __shared__ __align__(16) float sld[BT][64];      // last-day rows

  const int tid = threadIdx.x;
  const int row0 = blockIdx.x * BT;
  const int rb = tid & 3;    // 4 row-blocks of 4 rows
  const int cb = tid >> 2;   // 128 col-blocks of 4 cols
  const float b_out0 = b_out[0];

  // ---- constant staging + state init ----
  for (int i = tid; i < 1024; i += NTHR) sWc[i] = W_combine[i];
  for (int i = tid; i < 512; i += NTHR) { sbias_e[i] = bias_enc[i]; sbias_d[i] = bias_dec[i]; }
  for (int i = tid; i < 128; i += NTHR) { sWout[i] = W_out[i]; sbfirst[i] = b_first[i]; }
  for (int i = tid; i < 64; i += NTHR) sbcomb[i] = b_combine[i];
  for (int i = tid; i < 128 * BT; i += NTHR) (&u_t[64][0])[i] = 0.0f;  // h0 = 0
  for (int i = tid; i < BT * 128; i += NTHR) (&cst[0][0])[i] = 0.0f;   // c0 = 0
  for (int i = tid; i < BT * 64; i += NTHR) {
    int r = i >> 6, f = i & 63;
    sld[r][f] = a[((size_t)(row0 + r) * 365 + 364) * 64 + f];
  }

  // ---- helpers ----
  // GEMM: z[r][j] = bias[j] + sum_k u_t[off+k][r] * W[k][j]   (j over 512)
  auto do_matmul = [&](const float* __restrict__ bias, const float* __restrict__ Wa, int Ka,
                       int offa, const float* __restrict__ Wb, int Kb, int offb) {
    float acc[4][4];
#pragma unroll
    for (int i = 0; i < 4; ++i) {
      float bv0 = bias[cb * 4 + 0], bv1 = bias[cb * 4 + 1], bv2 = bias[cb * 4 + 2],
            bv3 = bias[cb * 4 + 3];
      acc[i][0] = bv0; acc[i][1] = bv1; acc[i][2] = bv2; acc[i][3] = bv3;
    }
    auto seg = [&](const float* __restrict__ W, int K, int off) {
      const float* ubase = &u_t[off][0];
#pragma unroll 8
      for (int k = 0; k < K; ++k) {
        const float4 u4 = *(const float4*)(ubase + k * BT + rb * 4);
        const float4 w4 = *(const float4*)(W + (size_t)k * 512 + cb * 4);
        float uu[4] = {u4.x, u4.y, u4.z, u4.w};
        float ww[4] = {w4.x, w4.y, w4.z, w4.w};
#pragma unroll
        for (int i = 0; i < 4; ++i)
#pragma unroll
          for (int c = 0; c < 4; ++c) acc[i][c] = fmaf(uu[i], ww[c], acc[i][c]);
      }
    };
    seg(Wa, Ka, offa);
    if (Wb) seg(Wb, Kb, offb);
#pragma unroll
    for (int i = 0; i < 4; ++i) {
      *(float4*)&zbuf[rb * 4 + i][cb * 4] =
          make_float4(acc[i][0], acc[i][1], acc[i][2], acc[i][3]);
    }
  };

  // gates -> c,h ; h written to u_t[hoff + n][r]; optional fused output dot
  auto cellupdate = [&](int hoff, bool do_out, int t) {
    const int r = tid >> 5;
    const int n0 = (tid & 31) * 4;
    float partial = 0.0f;
#pragma unroll
    for (int q = 0; q < 4; ++q) {
      int n = n0 + q;
      float zi = zbuf[r][n];
      float zf = zbuf[r][n + 128];
      float zg = zbuf[r][n + 256];
      float zo = zbuf[r][n + 384];
      float cn = sigf(zf) * cst[r][n] + sigf(zi) * tanhfast(zg);
      float h = sigf(zo) * tanhfast(cn);
      cst[r][n] = cn;
      u_t[hoff + n][r] = h;
      partial += h * sWout[n];
    }
    if (do_out) {
      partial += __shfl_down(partial, 16, 32);
      partial += __shfl_down(partial, 8, 32);
      partial += __shfl_down(partial, 4, 32);
      partial += __shfl_down(partial, 2, 32);
      partial += __shfl_down(partial, 1, 32);
      if ((tid & 31) == 0) out[(size_t)(row0 + r) * 30 + t] = partial + b_out0;
    }
  };

  // encoder step input -> u_t[0..63][r]
  auto loadx = [&](int s) {
    if (s < 8) {
      int day = (s == 0) ? 351 : 357 + s;  // seasonal (T-14) then last 7 days
      for (int idx = tid; idx < BT * 64; idx += NTHR) {
        int r = idx >> 6, f = idx & 63;
        u_t[f][r] = a[((size_t)(row0 + r) * 365 + day) * 64 + f];
      }
    } else {
      int sb = s - 8;
      for (int idx = tid; idx < BT * 64; idx += NTHR) {
        int r = idx >> 6, f = idx & 63;
        const float* brow = &b[((size_t)(row0 + r) * 8 + sb) * 16];
        float acc = sbcomb[f];
#pragma unroll
        for (int fb = 0; fb < 16; ++fb) acc = fmaf(brow[fb], sWc[fb * 64 + f], acc);
        u_t[f][r] = fmaxf(acc, 0.0f);
      }
    }
  };

  // x0 = relu(last_day @ W_first + b_first) -> u_t[0..127][r]
  auto x0phase = [&]() {
    for (int idx = tid; idx < BT * 128; idx += NTHR) {
      int r = idx >> 7, n = idx & 127;
      float acc = sbfirst[n];
#pragma unroll
      for (int k = 0; k < 64; ++k) acc = fmaf(sld[r][k], W_first[k * 128 + n], acc);
      u_t[n][r] = fmaxf(acc, 0.0f);
    }
  };

  loadx(0);
  __syncthreads();

  // ---- encoder: 16 steps ----
  for (int s = 0; s < 16; ++s) {
    do_matmul(sbias_e, Wk_enc, 64, 0, Wr_enc, 128, 64);
    __syncthreads();
    cellupdate(s == 15 ? 128 : 64, false, 0);
    if (s < 15) loadx(s + 1); else x0phase();
    __syncthreads();
  }

  // ---- decoder step 1: x0 @ Wk_dec + h_enc @ Wr_dec ----
  do_matmul(sbias_d, Wk_dec, 128, 0, Wr_dec, 128, 128);
  __syncthreads();
  cellupdate(0, true, 0);
  __syncthreads();

  // ---- decoder steps 2..30: input == hidden -> h @ (Wk+Wr) ----
  for (int t = 1; t < 30; ++t) {
    if constexpr (USE_WSUM) {
      do_matmul(sbias_d, Wsum, 128, 0, nullptr, 0, 0);
    } else {
      do_matmul(sbias_d, Wk_dec, 128, 0, Wr_dec, 128, 0);
    }
    __syncthreads();
    cellupdate(0, true, t);
    __syncthreads();
  }
}

extern "C" void kernel_launch(void* const* d_in, const int* in_sizes, int n_in,
                              void* d_out, int out_size, void* d_ws, size_t ws_size,
                              hipStream_t stream) {
  const float* a = (const float*)d_in[0];
  const float* b = (const float*)d_in[1];
  const float* W_combine = (const float*)d_in[2];
  const float* b_combine = (const float*)d_in[3];
  const float* W_first = (const float*)d_in[4];
  const float* b_first = (const float*)d_in[5];
  const float* Wk_enc = (const float*)d_in[6];
  const float* Wr_enc = (const float*)d_in[7];
  const float* bias_enc = (const float*)d_in[8];
  const float* Wk_dec = (const float*)d_in[9];
  const float* Wr_dec = (const float*)d_in[10];
  const float* bias_dec = (const float*)d_in[11];
  const float* W_out = (const float*)d_in[12];
  const float* b_out = (const float*)d_in[13];
  float* out = (float*)d_out;

  const bool use_wsum = (ws_size >= (size_t)(128 * 512 * sizeof(float)));
  if (use_wsum) {
    float* wsum = (float*)d_ws;
    wsum_kernel<<<256, 256, 0, stream>>>(Wk_dec, Wr_dec, wsum);
    ed_kernel<true><<<256, NTHR, 0, stream>>>(a, b, W_combine, b_combine, W_first, b_first,
                                              Wk_enc, Wr_enc, bias_enc, Wk_dec, Wr_dec,
                                              bias_dec, W_out, b_out, wsum, out);
  } else {
    ed_kernel<false><<<256, NTHR, 0, stream>>>(a, b, W_combine, b_combine, W_first, b_first,
                                               Wk_enc, Wr_enc, bias_enc, Wk_dec, Wr_dec,
                                               bias_dec, W_out, b_out, nullptr, out);
  }
}

// Round 2
// 656.561 us; speedup vs baseline: 1.4641x; 1.4641x over previous
//
#include <hip/hip_runtime.h>
#include <math.h>

typedef __attribute__((ext_vector_type(4))) float f32x4;
typedef __attribute__((ext_vector_type(8))) short s16x8;

#define NTHR 512
#define BT 16
#define KOPAD 33

// ws layout (ushort units)
#define OFF_ENC_H   0
#define OFF_ENC_L   98304
#define OFF_DEC1_H  196608
#define OFF_DEC1_L  327680
#define OFF_DSUM_H  458752
#define OFF_DSUM_L  524288
#define WS_USHORTS  589824

__device__ __forceinline__ float sigf(float x) { return 1.0f / (1.0f + __expf(-x)); }
__device__ __forceinline__ float tanhfast(float x) { return 2.0f / (1.0f + __expf(-2.0f * x)) - 1.0f; }

__device__ __forceinline__ unsigned short f2bf_hi(float x) {
  unsigned u = __float_as_uint(x);
  unsigned r = u + 0x7fffu + ((u >> 16) & 1u);
  return (unsigned short)(r >> 16);
}
__device__ __forceinline__ float bf2f(unsigned short h) {
  return __uint_as_float(((unsigned)h) << 16);
}

// ---------------- weight prep: fp32 -> B-fragment-ordered hi/lo bf16 ----------------
// frag elem e of a matrix: j=e&7, lane=(e>>3)&63, ct=(e>>9)&31, kt=e>>14
// value = W[kt*32 + (lane>>4)*8 + j][ct*16 + (lane&15)]
__global__ void prep_weights(const float* __restrict__ Wk_enc, const float* __restrict__ Wr_enc,
                             const float* __restrict__ Wk_dec, const float* __restrict__ Wr_dec,
                             unsigned short* __restrict__ ws) {
  int idx = blockIdx.x * blockDim.x + threadIdx.x;
  if (idx >= 294912) return;
  int m, e, hbase, lbase;
  if (idx < 98304)      { m = 0; e = idx;          hbase = OFF_ENC_H;  lbase = OFF_ENC_L; }
  else if (idx < 229376){ m = 1; e = idx - 98304;  hbase = OFF_DEC1_H; lbase = OFF_DEC1_L; }
  else                  { m = 2; e = idx - 229376; hbase = OFF_DSUM_H; lbase = OFF_DSUM_L; }
  int j = e & 7, l = (e >> 3) & 63, ct = (e >> 9) & 31, kt = e >> 14;
  int k = kt * 32 + ((l >> 4) << 3) + j;
  int c = (ct << 4) + (l & 15);
  float v;
  if (m == 0)      v = (k < 64)  ? Wk_enc[k * 512 + c] : Wr_enc[(k - 64) * 512 + c];
  else if (m == 1) v = (k < 128) ? Wk_dec[k * 512 + c] : Wr_dec[(k - 128) * 512 + c];
  else             v = Wk_dec[k * 512 + c] + Wr_dec[k * 512 + c];
  unsigned short hi = f2bf_hi(v);
  ws[hbase + e] = hi;
  ws[lbase + e] = f2bf_hi(v - bf2f(hi));
}

// ---------------- MFMA step: z[16][512] = u[16][K] @ W[K][512] + bias (3-pass hi/lo) ----
template <int KT>
__device__ __forceinline__ void mfma_step(
    const unsigned short* __restrict__ ahb, const unsigned short* __restrict__ alb,
    const unsigned short* __restrict__ BH, const unsigned short* __restrict__ BL,
    int lane, int wv, int rgrp,
    f32x4& aI, f32x4& aF, f32x4& aG, f32x4& aO) {
#pragma unroll
  for (int kt = 0; kt < KT; ++kt) {
    s16x8 ah = *(const s16x8*)(ahb + (kt * 4 + rgrp) * 8);
    s16x8 al = *(const s16x8*)(alb + (kt * 4 + rgrp) * 8);
    const unsigned short* baseh = BH + (size_t)kt * 16384 + lane * 8;
    const unsigned short* basel = BL + (size_t)kt * 16384 + lane * 8;
#pragma unroll
    for (int g = 0; g < 4; ++g) {
      int ct = g * 8 + wv;
      s16x8 bh = *(const s16x8*)(baseh + ct * 512);
      s16x8 bl = *(const s16x8*)(basel + ct * 512);
      f32x4& acc = (g == 0) ? aI : ((g == 1) ? aF : ((g == 2) ? aG : aO));
      acc = __builtin_amdgcn_mfma_f32_16x16x32_bf16(ah, bh, acc, 0, 0, 0);
      acc = __builtin_amdgcn_mfma_f32_16x16x32_bf16(ah, bl, acc, 0, 0, 0);
      acc = __builtin_amdgcn_mfma_f32_16x16x32_bf16(al, bh, acc, 0, 0, 0);
    }
  }
}

// ---------------- main fused kernel ----------------
__global__ __launch_bounds__(NTHR, 1) void ed_mfma(
    const float* __restrict__ a, const float* __restrict__ b,
    const float* __restrict__ W_combine, const float* __restrict__ b_combine,
    const float* __restrict__ W_first, const float* __restrict__ b_first,
    const float* __restrict__ bias_enc, const float* __restrict__ bias_dec,
    const float* __restrict__ W_out, const float* __restrict__ b_out,
    const unsigned short* __restrict__ wsB, float* __restrict__ out) {
  __shared__ __align__(16) unsigned short AhS[2][16][KOPAD][8];
  __shared__ __align__(16) unsigned short AlS[2][16][KOPAD][8];
  __shared__ float outp[30][8][16];
  __shared__ float sWc[16 * 64];
  __shared__ float sld[16][64];
  __shared__ float sbc[64];
  __shared__ float sbf[128];

  const int tid = threadIdx.x;
  const int lane = tid & 63;
  const int wv = tid >> 6;     // wave id 0..7
  const int rgrp = lane >> 4;  // 0..3
  const int cl = lane & 15;    // col-in-tile (gates) / A-row (matmul)
  const int n = wv * 16 + cl;  // hidden col owned by this lane
  const int row0 = blockIdx.x * BT;

  const float bei = bias_enc[n], bef = bias_enc[n + 128], beg = bias_enc[n + 256], beo = bias_enc[n + 384];
  const float bdi = bias_dec[n], bdf = bias_dec[n + 128], bdg = bias_dec[n + 256], bdo = bias_dec[n + 384];
  const float wout_n = W_out[n];
  const float b0 = b_out[0];
  float cstate[4] = {0.f, 0.f, 0.f, 0.f};

  // stage constants + init buffer 0 (x for s=0 at ko 0..7, h0=0 at ko 8..23)
  for (int i = tid; i < 1024; i += NTHR) sWc[i] = W_combine[i];
  for (int i = tid; i < 64; i += NTHR) sbc[i] = b_combine[i];
  for (int i = tid; i < 128; i += NTHR) sbf[i] = b_first[i];
  for (int i = tid; i < 1024; i += NTHR) {
    int r = i >> 6, f = i & 63;
    sld[r][f] = a[((size_t)(row0 + r) * 365 + 364) * 64 + f];
  }
  for (int i = tid; i < 1024; i += NTHR) {
    int r = i >> 6, f = i & 63;
    float v = a[((size_t)(row0 + r) * 365 + 351) * 64 + f];
    unsigned short hh = f2bf_hi(v);
    AhS[0][r][f >> 3][f & 7] = hh;
    AlS[0][r][f >> 3][f & 7] = f2bf_hi(v - bf2f(hh));
  }
  for (int i = tid; i < 2048; i += NTHR) {  // h0 zeros: 16 rows x 16 octets x 8
    int r = i >> 7, ko = 8 + ((i >> 3) & 15), j = i & 7;
    AhS[0][r][ko][j] = 0;
    AlS[0][r][ko][j] = 0;
  }

  // h(+x) producer helpers -----------------------------------------------------
  auto cell = [&](f32x4 aI, f32x4 aF, f32x4 aG, f32x4 aO, int np, int kob, int t, bool dout) {
    float po[4];
#pragma unroll
    for (int q = 0; q < 4; ++q) {
      float ci = sigf(aI[q]);
      float cf = sigf(aF[q]);
      float cg = tanhfast(aG[q]);
      float co = sigf(aO[q]);
      float cn = cf * cstate[q] + ci * cg;
      cstate[q] = cn;
      float h = co * tanhfast(cn);
      int r = rgrp * 4 + q;
      unsigned short hh = f2bf_hi(h);
      AhS[np][r][kob + (n >> 3)][n & 7] = hh;
      AlS[np][r][kob + (n >> 3)][n & 7] = f2bf_hi(h - bf2f(hh));
      po[q] = h * wout_n;
    }
    if (dout) {
#pragma unroll
      for (int q = 0; q < 4; ++q) {
        float p = po[q];
        p += __shfl_xor(p, 1, 64);
        p += __shfl_xor(p, 2, 64);
        p += __shfl_xor(p, 4, 64);
        p += __shfl_xor(p, 8, 64);
        if (cl == 0) outp[t][wv][rgrp * 4 + q] = p;
      }
    }
  };

  auto loadx = [&](int s, int np) {
    if (s < 8) {
      int day = (s == 0) ? 351 : (357 + s);
      for (int i = tid; i < 1024; i += NTHR) {
        int r = i >> 6, f = i & 63;
        float v = a[((size_t)(row0 + r) * 365 + day) * 64 + f];
        unsigned short hh = f2bf_hi(v);
        AhS[np][r][f >> 3][f & 7] = hh;
        AlS[np][r][f >> 3][f & 7] = f2bf_hi(v - bf2f(hh));
      }
    } else {
      int sb = s - 8;
      for (int i = tid; i < 1024; i += NTHR) {
        int r = i >> 6, f = i & 63;
        const float* br = &b[((size_t)(row0 + r) * 8 + sb) * 16];
        float acc2 = sbc[f];
#pragma unroll
        for (int k2 = 0; k2 < 16; ++k2) acc2 = fmaf(br[k2], sWc[k2 * 64 + f], acc2);
        acc2 = fmaxf(acc2, 0.f);
        unsigned short hh = f2bf_hi(acc2);
        AhS[np][r][f >> 3][f & 7] = hh;
        AlS[np][r][f >> 3][f & 7] = f2bf_hi(acc2 - bf2f(hh));
      }
    }
  };

  auto x0phase = [&](int np) {
    for (int i = tid; i < 2048; i += NTHR) {
      int r = i >> 7, nn = i & 127;
      float acc2 = sbf[nn];
#pragma unroll
      for (int k2 = 0; k2 < 64; ++k2) acc2 = fmaf(sld[r][k2], W_first[k2 * 128 + nn], acc2);
      acc2 = fmaxf(acc2, 0.f);
      unsigned short hh = f2bf_hi(acc2);
      AhS[np][r][nn >> 3][nn & 7] = hh;
      AlS[np][r][nn >> 3][nn & 7] = f2bf_hi(acc2 - bf2f(hh));
    }
  };

  // ------------------------- time loop -------------------------
  int par = 0;
  f32x4 aI, aF, aG, aO;

  // encoder: 16 steps, K=192 (x octets 0..7, h octets 8..23)
  for (int s = 0; s < 16; ++s) {
    __syncthreads();
    aI = (f32x4){bei, bei, bei, bei};
    aF = (f32x4){bef, bef, bef, bef};
    aG = (f32x4){beg, beg, beg, beg};
    aO = (f32x4){beo, beo, beo, beo};
    mfma_step<6>(&AhS[par][cl][0][0], &AlS[par][cl][0][0],
                 wsB + OFF_ENC_H, wsB + OFF_ENC_L, lane, wv, rgrp, aI, aF, aG, aO);
    int np = par ^ 1;
    cell(aI, aF, aG, aO, np, (s < 15) ? 8 : 16, 0, false);
    if (s < 15) loadx(s + 1, np); else x0phase(np);
    par = np;
  }

  // decoder step 1: K=256 (x0 octets 0..15, h_enc octets 16..31)
  {
    __syncthreads();
    aI = (f32x4){bdi, bdi, bdi, bdi};
    aF = (f32x4){bdf, bdf, bdf, bdf};
    aG = (f32x4){bdg, bdg, bdg, bdg};
    aO = (f32x4){bdo, bdo, bdo, bdo};
    mfma_step<8>(&AhS[par][cl][0][0], &AlS[par][cl][0][0],
                 wsB + OFF_DEC1_H, wsB + OFF_DEC1_L, lane, wv, rgrp, aI, aF, aG, aO);
    int np = par ^ 1;
    cell(aI, aF, aG, aO, np, 0, 0, true);
    par = np;
  }

  // decoder steps 2..30: K=128, W = Wk+Wr (input == hidden)
  for (int t = 1; t < 30; ++t) {
    __syncthreads();
    aI = (f32x4){bdi, bdi, bdi, bdi};
    aF = (f32x4){bdf, bdf, bdf, bdf};
    aG = (f32x4){bdg, bdg, bdg, bdg};
    aO = (f32x4){bdo, bdo, bdo, bdo};
    mfma_step<4>(&AhS[par][cl][0][0], &AlS[par][cl][0][0],
                 wsB + OFF_DSUM_H, wsB + OFF_DSUM_L, lane, wv, rgrp, aI, aF, aG, aO);
    int np = par ^ 1;
    cell(aI, aF, aG, aO, np, 0, t, true);
    par = np;
  }

  // final: out[r][t] = b0 + sum_w outp[t][w][r]
  __syncthreads();
  if (tid < 480) {
    int r = tid / 30, t = tid % 30;
    float s2 = b0;
#pragma unroll
    for (int w2 = 0; w2 < 8; ++w2) s2 += outp[t][w2][r];
    out[(size_t)(row0 + r) * 30 + t] = s2;
  }
}

// ---------------- fp32 fallback (known-good from round 1) ----------------
__global__ __launch_bounds__(NTHR, 1) void ed_fallback(
    const float* __restrict__ a, const float* __restrict__ b,
    const float* __restrict__ W_combine, const float* __restrict__ b_combine,
    const float* __restrict__ W_first, const float* __restrict__ b_first,
    const float* __restrict__ Wk_enc, const float* __restrict__ Wr_enc,
    const float* __restrict__ bias_enc, const float* __restrict__ Wk_dec,
    const float* __restrict__ Wr_dec, const float* __restrict__ bias_dec,
    const float* __restrict__ W_out, const float* __restrict__ b_out,
    float* __restrict__ out) {
  __shared__ __align__(16) float u_t[256][BT];
  __shared__ __align__(16) float zbuf[BT][512];
  __shared__ __align__(16) float cst[BT][128];
  __shared__ __align__(16) float sWc[16 * 64];
  __shared__ float sbias_e[512];
  __shared__ float sbias_d[512];
  __shared__ float sWout[128];
  __shared__ float sbcomb[64];
  __shared__ float sbfirst[128];
  __shared__ __align__(16) float sld[BT][64];

  const int tid = threadIdx.x;
  const int row0 = blockIdx.x * BT;
  const int rb = tid & 3;
  const int cb = tid >> 2;
  const float b_out0 = b_out[0];

  for (int i = tid; i < 1024; i += NTHR) sWc[i] = W_combine[i];
  for (int i = tid; i < 512; i += NTHR) { sbias_e[i] = bias_enc[i]; sbias_d[i] = bias_dec[i]; }
  for (int i = tid; i < 128; i += NTHR) { sWout[i] = W_out[i]; sbfirst[i] = b_first[i]; }
  for (int i = tid; i < 64; i += NTHR) sbcomb[i] = b_combine[i];
  for (int i = tid; i < 128 * BT; i += NTHR) (&u_t[64][0])[i] = 0.0f;
  for (int i = tid; i < BT * 128; i += NTHR) (&cst[0][0])[i] = 0.0f;
  for (int i = tid; i < BT * 64; i += NTHR) {
    int r = i >> 6, f = i & 63;
    sld[r][f] = a[((size_t)(row0 + r) * 365 + 364) * 64 + f];
  }

  auto do_matmul = [&](const float* bias, const float* Wa, int Ka, int offa,
                       const float* Wb, int Kb, int offb) {
    float acc[4][4];
#pragma unroll
    for (int i = 0; i < 4; ++i) {
      acc[i][0] = bias[cb * 4 + 0]; acc[i][1] = bias[cb * 4 + 1];
      acc[i][2] = bias[cb * 4 + 2]; acc[i][3] = bias[cb * 4 + 3];
    }
    auto seg = [&](const float* W, int K, int off) {
      const float* ubase = &u_t[off][0];
#pragma unroll 8
      for (int k = 0; k < K; ++k) {
        const float4 u4 = *(const float4*)(ubase + k * BT + rb * 4);
        const float4 w4 = *(const float4*)(W + (size_t)k * 512 + cb * 4);
        float uu[4] = {u4.x, u4.y, u4.z, u4.w};
        float ww[4] = {w4.x, w4.y, w4.z, w4.w};
#pragma unroll
        for (int i = 0; i < 4; ++i)
#pragma unroll
          for (int c = 0; c < 4; ++c) acc[i][c] = fmaf(uu[i], ww[c], acc[i][c]);
      }
    };
    seg(Wa, Ka, offa);
    if (Wb) seg(Wb, Kb, offb);
#pragma unroll
    for (int i = 0; i < 4; ++i)
      *(float4*)&zbuf[rb * 4 + i][cb * 4] = make_float4(acc[i][0], acc[i][1], acc[i][2], acc[i][3]);
  };

  auto cellupdate = [&](int hoff, bool do_out, int t) {
    const int r = tid >> 5;
    const int n0 = (tid & 31) * 4;
    float partial = 0.0f;
#pragma unroll
    for (int q = 0; q < 4; ++q) {
      int n = n0 + q;
      float zi = zbuf[r][n], zf = zbuf[r][n + 128], zg = zbuf[r][n + 256], zo = zbuf[r][n + 384];
      float cn = sigf(zf) * cst[r][n] + sigf(zi) * tanhfast(zg);
      float h = sigf(zo) * tanhfast(cn);
      cst[r][n] = cn;
      u_t[hoff + n][r] = h;
      partial += h * sWout[n];
    }
    if (do_out) {
      partial += __shfl_down(partial, 16, 32);
      partial += __shfl_down(partial, 8, 32);
      partial += __shfl_down(partial, 4, 32);
      partial += __shfl_down(partial, 2, 32);
      partial += __shfl_down(partial, 1, 32);
      if ((tid & 31) == 0) out[(size_t)(row0 + r) * 30 + t] = partial + b_out0;
    }
  };

  auto loadx = [&](int s) {
    if (s < 8) {
      int day = (s == 0) ? 351 : 357 + s;
      for (int idx = tid; idx < BT * 64; idx += NTHR) {
        int r = idx >> 6, f = idx & 63;
        u_t[f][r] = a[((size_t)(row0 + r) * 365 + day) * 64 + f];
      }
    } else {
      int sb = s - 8;
      for (int idx = tid; idx < BT * 64; idx += NTHR) {
        int r = idx >> 6, f = idx & 63;
        const float* brow = &b[((size_t)(row0 + r) * 8 + sb) * 16];
        float acc = sbcomb[f];
#pragma unroll
        for (int fb = 0; fb < 16; ++fb) acc = fmaf(brow[fb], sWc[fb * 64 + f], acc);
        u_t[f][r] = fmaxf(acc, 0.0f);
      }
    }
  };

  auto x0phase = [&]() {
    for (int idx = tid; idx < BT * 128; idx += NTHR) {
      int r = idx >> 7, n = idx & 127;
      float acc = sbfirst[n];
#pragma unroll
      for (int k = 0; k < 64; ++k) acc = fmaf(sld[r][k], W_first[k * 128 + n], acc);
      u_t[n][r] = fmaxf(acc, 0.0f);
    }
  };

  loadx(0);
  __syncthreads();
  for (int s = 0; s < 16; ++s) {
    do_matmul(sbias_e, Wk_enc, 64, 0, Wr_enc, 128, 64);
    __syncthreads();
    cellupdate(s == 15 ? 128 : 64, false, 0);
    if (s < 15) loadx(s + 1); else x0phase();
    __syncthreads();
  }
  do_matmul(sbias_d, Wk_dec, 128, 0, Wr_dec, 128, 128);
  __syncthreads();
  cellupdate(0, true, 0);
  __syncthreads();
  for (int t = 1; t < 30; ++t) {
    do_matmul(sbias_d, Wk_dec, 128, 0, Wr_dec, 128, 0);
    __syncthreads();
    cellupdate(0, true, t);
    __syncthreads();
  }
}

extern "C" void kernel_launch(void* const* d_in, const int* in_sizes, int n_in,
                              void* d_out, int out_size, void* d_ws, size_t ws_size,
                              hipStream_t stream) {
  const float* a = (const float*)d_in[0];
  const float* b = (const float*)d_in[1];
  const float* W_combine = (const float*)d_in[2];
  const float* b_combine = (const float*)d_in[3];
  const float* W_first = (const float*)d_in[4];
  const float* b_first = (const float*)d_in[5];
  const float* Wk_enc = (const float*)d_in[6];
  const float* Wr_enc = (const float*)d_in[7];
  const float* bias_enc = (const float*)d_in[8];
  const float* Wk_dec = (const float*)d_in[9];
  const float* Wr_dec = (const float*)d_in[10];
  const float* bias_dec = (const float*)d_in[11];
  const float* W_out = (const float*)d_in[12];
  const float* b_out = (const float*)d_in[13];
  float* out = (float*)d_out;

  if (ws_size >= (size_t)WS_USHORTS * sizeof(unsigned short)) {
    unsigned short* wsB = (unsigned short*)d_ws;
    prep_weights<<<1152, 256, 0, stream>>>(Wk_enc, Wr_enc, Wk_dec, Wr_dec, wsB);
    ed_mfma<<<256, NTHR, 0, stream>>>(a, b, W_combine, b_combine, W_first, b_first,
                                      bias_enc, bias_dec, W_out, b_out, wsB, out);
  } else {
    ed_fallback<<<256, NTHR, 0, stream>>>(a, b, W_combine, b_combine, W_first, b_first,
                                          Wk_enc, Wr_enc, bias_enc, Wk_dec, Wr_dec,
                                          bias_dec, W_out, b_out, out);
  }
}

// Round 6
// 609.889 us; speedup vs baseline: 1.5761x; 1.0765x over previous
//
#include <hip/hip_runtime.h>
#include <hip/hip_fp16.h>
#include <math.h>

typedef __attribute__((ext_vector_type(4))) float f32x4;
typedef __attribute__((ext_vector_type(8))) _Float16 f16x8;

#define NTHR 1024

// ws layout in ushort units (fp16 weights, B-fragment order)
#define OFF_ENC   0        // kt 0..5  (K=192: x 8 octets + h 16 octets)
#define OFF_DEC1  98304    // kt 0..7  (K=256: x0 16 + h 16)
#define OFF_DSUM  229376   // kt 0..3  (K=128: h, Wk+Wr)
#define WS_USHORTS 294912

__device__ __forceinline__ float sigf(float x) { return 1.0f / (1.0f + __expf(-x)); }
__device__ __forceinline__ float tanhfast(float x) { return 2.0f / (1.0f + __expf(-2.0f * x)) - 1.0f; }

__device__ __forceinline__ unsigned short f2h(float x) {
  _Float16 h = (_Float16)x; unsigned short u; __builtin_memcpy(&u, &h, 2); return u;
}
__device__ __forceinline__ float h2f(unsigned short u) {
  _Float16 h; __builtin_memcpy(&h, &u, 2); return (float)h;
}

// ---------------- weight prep: fp32 -> fp16 B-fragment order ----------------
// octet (kt,ct,lane): ushort off = base + kt*16384 + ct*512 + lane*8 + j
// value = W[kt*32 + (lane>>4)*8 + j][ct*16 + (lane&15)]
__global__ void prep_weights(const float* __restrict__ Wk_enc, const float* __restrict__ Wr_enc,
                             const float* __restrict__ Wk_dec, const float* __restrict__ Wr_dec,
                             unsigned short* __restrict__ ws) {
  int o = blockIdx.x * blockDim.x + threadIdx.x;
  if (o >= 36864) return;
  int m, oo, base;
  if (o < 12288)      { m = 0; oo = o;         base = OFF_ENC; }
  else if (o < 28672) { m = 1; oo = o - 12288; base = OFF_DEC1; }
  else                { m = 2; oo = o - 28672; base = OFF_DSUM; }
  int l = oo & 63, ct = (oo >> 6) & 31, kt = oo >> 11;
  int c = ct * 16 + (l & 15);
  int kb = kt * 32 + ((l >> 4) << 3);
  unsigned short v[8];
#pragma unroll
  for (int j = 0; j < 8; ++j) {
    int k = kb + j;
    float w;
    if (m == 0)      w = (k < 64)  ? Wk_enc[k * 512 + c] : Wr_enc[(k - 64) * 512 + c];
    else if (m == 1) w = (k < 128) ? Wk_dec[k * 512 + c] : Wr_dec[(k - 128) * 512 + c];
    else             w = Wk_dec[k * 512 + c] + Wr_dec[k * 512 + c];
    v[j] = f2h(w);
  }
  uint4 pack; __builtin_memcpy(&pack, v, 16);
  *(uint4*)(ws + (size_t)base + (size_t)kt * 16384 + ct * 512 + l * 8) = pack;
}

// ---------------- MFMA phase: acc += u[16][K] @ W[K][32-col-slice], 2-pass hi/res ----
template <int KT>
__device__ __forceinline__ void mm(const unsigned short* __restrict__ ah_base,
                                   const unsigned short* __restrict__ al_base,
                                   const unsigned short* __restrict__ bbase, int rgrp,
                                   f32x4& acc0, f32x4& acc1) {
#pragma unroll
  for (int kt = 0; kt < KT; ++kt) {
    const int ko = kt * 4 + rgrp;
    f16x8 a_h = *(const f16x8*)(ah_base + ko * 8);
    f16x8 a_l = *(const f16x8*)(al_base + ko * 8);
    const unsigned short* bp = bbase + (size_t)kt * 16384;
    f16x8 b0 = *(const f16x8*)(bp);
    f16x8 b1 = *(const f16x8*)(bp + 512);
    acc0 = __builtin_amdgcn_mfma_f32_16x16x32_f16(a_h, b0, acc0, 0, 0, 0);
    acc0 = __builtin_amdgcn_mfma_f32_16x16x32_f16(a_l, b0, acc0, 0, 0, 0);
    acc1 = __builtin_amdgcn_mfma_f32_16x16x32_f16(a_h, b1, acc1, 0, 0, 0);
    acc1 = __builtin_amdgcn_mfma_f32_16x16x32_f16(a_l, b1, acc1, 0, 0, 0);
  }
}

// ---------------- main fused kernel: 16 waves, 1 WG/CU ----------------
__global__ __launch_bounds__(NTHR) void ed_mfma(
    const float* __restrict__ a, const float* __restrict__ b,
    const float* __restrict__ W_combine, const float* __restrict__ b_combine,
    const float* __restrict__ W_first, const float* __restrict__ b_first,
    const float* __restrict__ bias_enc, const float* __restrict__ bias_dec,
    const float* __restrict__ W_out, const float* __restrict__ b_out,
    const unsigned short* __restrict__ wsB, float* __restrict__ out) {
  __shared__ __align__(16) float zbuf[16][516];            // 33 KB, pad->2-way banks
  __shared__ __align__(16) unsigned short Ah[16][33][8];   // u hi (fp16 bits)
  __shared__ __align__(16) unsigned short Al[16][33][8];   // u residual
  __shared__ float sbe[512], sbd[512];
  __shared__ __align__(16) float sWc[1024];
  __shared__ __align__(16) float sld[16][64];
  __shared__ float sWout[128];
  __shared__ float sbc[64], sbf[128];

  const int tid = threadIdx.x;
  const int lane = tid & 63;
  const int wv = tid >> 6;       // 0..15: matmul ct-pair owner; cell row owner
  const int cl = lane & 15;      // A row in matmul
  const int rgrp = lane >> 4;
  const int ct0 = wv * 2;
  const int row0 = blockIdx.x * 16;
  const float b0 = b_out[0];

  // ---- staging + init ----
  for (int i = tid; i < 1024; i += NTHR) sWc[i] = W_combine[i];
  for (int i = tid; i < 512; i += NTHR) { sbe[i] = bias_enc[i]; sbd[i] = bias_dec[i]; }
  for (int i = tid; i < 128; i += NTHR) { sWout[i] = W_out[i]; sbf[i] = b_first[i]; }
  for (int i = tid; i < 64; i += NTHR) sbc[i] = b_combine[i];
  {
    int r = tid >> 6, f = tid & 63;
    sld[r][f] = a[((size_t)(row0 + r) * 365 + 364) * 64 + f];
    float v = a[((size_t)(row0 + r) * 365 + 351) * 64 + f];  // seasonal, step 0
    unsigned short hh = f2h(v);
    Ah[r][f >> 3][f & 7] = hh;
    Al[r][f >> 3][f & 7] = f2h(v - h2f(hh));
  }
  for (int i = tid; i < 2048; i += NTHR) {  // h0 = 0 at octets 8..23
    int r = i >> 7, ko = 8 + ((i >> 3) & 15), j = i & 7;
    Ah[r][ko][j] = 0; Al[r][ko][j] = 0;
  }
  float cs0 = 0.f, cs1 = 0.f;

  const unsigned short* ah_base = &Ah[cl][0][0];
  const unsigned short* al_base = &Al[cl][0][0];
  const unsigned short* benc  = wsB + OFF_ENC  + ct0 * 512 + lane * 8;
  const unsigned short* bdec1 = wsB + OFF_DEC1 + ct0 * 512 + lane * 8;
  const unsigned short* bdsum = wsB + OFF_DSUM + ct0 * 512 + lane * 8;

  auto zwrite = [&](const f32x4& acc0, const f32x4& acc1) {
#pragma unroll
    for (int q = 0; q < 4; ++q) {
      zbuf[rgrp * 4 + q][ct0 * 16 + cl] = acc0[q];
      zbuf[rgrp * 4 + q][ct0 * 16 + 16 + cl] = acc1[q];
    }
  };

  // cell: wave wv owns row r=wv; lane owns hidden n0=lane, n1=lane+64
  auto cell = [&](const float* __restrict__ sb, int kob, bool dout, int t) {
    const int r = wv, n0 = lane, n1 = lane + 64;
    float zi0 = zbuf[r][n0] + sb[n0];
    float zf0 = zbuf[r][n0 + 128] + sb[n0 + 128];
    float zg0 = zbuf[r][n0 + 256] + sb[n0 + 256];
    float zo0 = zbuf[r][n0 + 384] + sb[n0 + 384];
    float zi1 = zbuf[r][n1] + sb[n1];
    float zf1 = zbuf[r][n1 + 128] + sb[n1 + 128];
    float zg1 = zbuf[r][n1 + 256] + sb[n1 + 256];
    float zo1 = zbuf[r][n1 + 384] + sb[n1 + 384];
    cs0 = sigf(zf0) * cs0 + sigf(zi0) * tanhfast(zg0);
    cs1 = sigf(zf1) * cs1 + sigf(zi1) * tanhfast(zg1);
    float h0 = sigf(zo0) * tanhfast(cs0);
    float h1 = sigf(zo1) * tanhfast(cs1);
    unsigned short hh0 = f2h(h0), hh1 = f2h(h1);
    Ah[r][kob + (n0 >> 3)][n0 & 7] = hh0;
    Al[r][kob + (n0 >> 3)][n0 & 7] = f2h(h0 - h2f(hh0));
    Ah[r][kob + (n1 >> 3)][n1 & 7] = hh1;
    Al[r][kob + (n1 >> 3)][n1 & 7] = f2h(h1 - h2f(hh1));
    if (dout) {
      float p = h0 * sWout[n0] + h1 * sWout[n1];
      p += __shfl_xor(p, 1);
      p += __shfl_xor(p, 2);
      p += __shfl_xor(p, 4);
      p += __shfl_xor(p, 8);
      p += __shfl_xor(p, 16);
      p += __shfl_xor(p, 32);
      if (lane == 0) out[(size_t)(row0 + r) * 30 + t] = p + b0;
    }
  };

  auto loadx = [&](int s) {  // s in 1..15: write next x into octets 0..7
    int r = tid >> 6, f = tid & 63;
    float v;
    if (s < 8) {
      v = a[((size_t)(row0 + r) * 365 + (357 + s)) * 64 + f];
    } else {
      const float* br = &b[((size_t)(row0 + r) * 8 + (s - 8)) * 16];
      float acc = sbc[f];
#pragma unroll
      for (int fb = 0; fb < 16; ++fb) acc = fmaf(br[fb], sWc[fb * 64 + f], acc);
      v = fmaxf(acc, 0.f);
    }
    unsigned short hh = f2h(v);
    Ah[r][f >> 3][f & 7] = hh;
    Al[r][f >> 3][f & 7] = f2h(v - h2f(hh));
  };

  auto x0phase = [&]() {  // x0 = relu(last_day @ W_first + b_first) -> octets 0..15
    for (int i = tid; i < 2048; i += NTHR) {
      int r = i >> 7, nn = i & 127;
      float acc = sbf[nn];
#pragma unroll
      for (int k = 0; k < 64; ++k) acc = fmaf(sld[r][k], W_first[k * 128 + nn], acc);
      acc = fmaxf(acc, 0.f);
      unsigned short hh = f2h(acc);
      Ah[r][nn >> 3][nn & 7] = hh;
      Al[r][nn >> 3][nn & 7] = f2h(acc - h2f(hh));
    }
  };

  __syncthreads();

  // ---- encoder: 16 steps, K=192 ----
  for (int s = 0; s < 16; ++s) {
    f32x4 acc0 = {0.f, 0.f, 0.f, 0.f}, acc1 = {0.f, 0.f, 0.f, 0.f};
    mm<6>(ah_base, al_base, benc, rgrp, acc0, acc1);
    zwrite(acc0, acc1);
    __syncthreads();
    cell(sbe, (s < 15) ? 8 : 16, false, 0);
    if (s < 15) loadx(s + 1); else x0phase();
    __syncthreads();
  }

  // ---- decoder step 1: K=256 ----
  {
    f32x4 acc0 = {0.f, 0.f, 0.f, 0.f}, acc1 = {0.f, 0.f, 0.f, 0.f};
    mm<8>(ah_base, al_base, bdec1, rgrp, acc0, acc1);
    zwrite(acc0, acc1);
    __syncthreads();
    cell(sbd, 0, true, 0);
    __syncthreads();
  }

  // ---- decoder steps 2..30: K=128, W = Wk+Wr ----
  for (int t = 1; t < 30; ++t) {
    f32x4 acc0 = {0.f, 0.f, 0.f, 0.f}, acc1 = {0.f, 0.f, 0.f, 0.f};
    mm<4>(ah_base, al_base, bdsum, rgrp, acc0, acc1);
    zwrite(acc0, acc1);
    __syncthreads();
    cell(sbd, 0, true, t);
    __syncthreads();
  }
}

// ---------------- fp32 fallback (known-good round-1 kernel) ----------------
#define FNTHR 512
__global__ __launch_bounds__(FNTHR, 1) void ed_fallback(
    const float* __restrict__ a, const float* __restrict__ b,
    const float* __restrict__ W_combine, const float* __restrict__ b_combine,
    const float* __restrict__ W_first, const float* __restrict__ b_first,
    const float* __restrict__ Wk_enc, const float* __restrict__ Wr_enc,
    const float* __restrict__ bias_enc, const float* __restrict__ Wk_dec,
    const float* __restrict__ Wr_dec, const float* __restrict__ bias_dec,
    const float* __restrict__ W_out, const float* __restrict__ b_out,
    float* __restrict__ out) {
  __shared__ __align__(16) float u_t[256][16];
  __shared__ __align__(16) float zbuf[16][512];
  __shared__ __align__(16) float cst[16][128];
  __shared__ __align__(16) float sWc[16 * 64];
  __shared__ float sbias_e[512];
  __shared__ float sbias_d[512];
  __shared__ float sWout[128];
  __shared__ float sbcomb[64];
  __shared__ float sbfirst[128];
  __shared__ __align__(16) float sld[16][64];

  const int tid = threadIdx.x;
  const int row0 = blockIdx.x * 16;
  const int rb = tid & 3;
  const int cb = tid >> 2;
  const float b_out0 = b_out[0];

  for (int i = tid; i < 1024; i += FNTHR) sWc[i] = W_combine[i];
  for (int i = tid; i < 512; i += FNTHR) { sbias_e[i] = bias_enc[i]; sbias_d[i] = bias_dec[i]; }
  for (int i = tid; i < 128; i += FNTHR) { sWout[i] = W_out[i]; sbfirst[i] = b_first[i]; }
  for (int i = tid; i < 64; i += FNTHR) sbcomb[i] = b_combine[i];
  for (int i = tid; i < 128 * 16; i += FNTHR) (&u_t[64][0])[i] = 0.0f;
  for (int i = tid; i < 16 * 128; i += FNTHR) (&cst[0][0])[i] = 0.0f;
  for (int i = tid; i < 16 * 64; i += FNTHR) {
    int r = i >> 6, f = i & 63;
    sld[r][f] = a[((size_t)(row0 + r) * 365 + 364) * 64 + f];
  }

  auto do_matmul = [&](const float* bias, const float* Wa, int Ka, int offa,
                       const float* Wb, int Kb, int offb) {
    float acc[4][4];
#pragma unroll
    for (int i = 0; i < 4; ++i) {
      acc[i][0] = bias[cb * 4 + 0]; acc[i][1] = bias[cb * 4 + 1];
      acc[i][2] = bias[cb * 4 + 2]; acc[i][3] = bias[cb * 4 + 3];
    }
    auto seg = [&](const float* W, int K, int off) {
      const float* ubase = &u_t[off][0];
#pragma unroll 8
      for (int k = 0; k < K; ++k) {
        const float4 u4 = *(const float4*)(ubase + k * 16 + rb * 4);
        const float4 w4 = *(const float4*)(W + (size_t)k * 512 + cb * 4);
        float uu[4] = {u4.x, u4.y, u4.z, u4.w};
        float ww[4] = {w4.x, w4.y, w4.z, w4.w};
#pragma unroll
        for (int i = 0; i < 4; ++i)
#pragma unroll
          for (int c = 0; c < 4; ++c) acc[i][c] = fmaf(uu[i], ww[c], acc[i][c]);
      }
    };
    seg(Wa, Ka, offa);
    if (Wb) seg(Wb, Kb, offb);
#pragma unroll
    for (int i = 0; i < 4; ++i)
      *(float4*)&zbuf[rb * 4 + i][cb * 4] = make_float4(acc[i][0], acc[i][1], acc[i][2], acc[i][3]);
  };

  auto cellupdate = [&](int hoff, bool do_out, int t) {
    const int r = tid >> 5;
    const int n0 = (tid & 31) * 4;
    float partial = 0.0f;
#pragma unroll
    for (int q = 0; q < 4; ++q) {
      int n = n0 + q;
      float zi = zbuf[r][n], zf = zbuf[r][n + 128], zg = zbuf[r][n + 256], zo = zbuf[r][n + 384];
      float cn = sigf(zf) * cst[r][n] + sigf(zi) * tanhfast(zg);
      float h = sigf(zo) * tanhfast(cn);
      cst[r][n] = cn;
      u_t[hoff + n][r] = h;
      partial += h * sWout[n];
    }
    if (do_out) {
      partial += __shfl_down(partial, 16, 32);
      partial += __shfl_down(partial, 8, 32);
      partial += __shfl_down(partial, 4, 32);
      partial += __shfl_down(partial, 2, 32);
      partial += __shfl_down(partial, 1, 32);
      if ((tid & 31) == 0) out[(size_t)(row0 + r) * 30 + t] = partial + b_out0;
    }
  };

  auto loadx = [&](int s) {
    if (s < 8) {
      int day = (s == 0) ? 351 : 357 + s;
      for (int idx = tid; idx < 16 * 64; idx += FNTHR) {
        int r = idx >> 6, f = idx & 63;
        u_t[f][r] = a[((size_t)(row0 + r) * 365 + day) * 64 + f];
      }
    } else {
      int sb = s - 8;
      for (int idx = tid; idx < 16 * 64; idx += FNTHR) {
        int r = idx >> 6, f = idx & 63;
        const float* brow = &b[((size_t)(row0 + r) * 8 + sb) * 16];
        float acc = sbcomb[f];
#pragma unroll
        for (int fb = 0; fb < 16; ++fb) acc = fmaf(brow[fb], sWc[fb * 64 + f], acc);
        u_t[f][r] = fmaxf(acc, 0.0f);
      }
    }
  };

  auto x0phase = [&]() {
    for (int idx = tid; idx < 16 * 128; idx += FNTHR) {
      int r = idx >> 7, n = idx & 127;
      float acc = sbfirst[n];
#pragma unroll
      for (int k = 0; k < 64; ++k) acc = fmaf(sld[r][k], W_first[k * 128 + n], acc);
      u_t[n][r] = fmaxf(acc, 0.0f);
    }
  };

  loadx(0);
  __syncthreads();
  for (int s = 0; s < 16; ++s) {
    do_matmul(sbias_e, Wk_enc, 64, 0, Wr_enc, 128, 64);
    __syncthreads();
    cellupdate(s == 15 ? 128 : 64, false, 0);
    if (s < 15) loadx(s + 1); else x0phase();
    __syncthreads();
  }
  do_matmul(sbias_d, Wk_dec, 128, 0, Wr_dec, 128, 128);
  __syncthreads();
  cellupdate(0, true, 0);
  __syncthreads();
  for (int t = 1; t < 30; ++t) {
    do_matmul(sbias_d, Wk_dec, 128, 0, Wr_dec, 128, 0);
    __syncthreads();
    cellupdate(0, true, t);
    __syncthreads();
  }
}

extern "C" void kernel_launch(void* const* d_in, const int* in_sizes, int n_in,
                              void* d_out, int out_size, void* d_ws, size_t ws_size,
                              hipStream_t stream) {
  const float* a = (const float*)d_in[0];
  const float* b = (const float*)d_in[1];
  const float* W_combine = (const float*)d_in[2];
  const float* b_combine = (const float*)d_in[3];
  const float* W_first = (const float*)d_in[4];
  const float* b_first = (const float*)d_in[5];
  const float* Wk_enc = (const float*)d_in[6];
  const float* Wr_enc = (const float*)d_in[7];
  const float* bias_enc = (const float*)d_in[8];
  const float* Wk_dec = (const float*)d_in[9];
  const float* Wr_dec = (const float*)d_in[10];
  const float* bias_dec = (const float*)d_in[11];
  const float* W_out = (const float*)d_in[12];
  const float* b_out = (const float*)d_in[13];
  float* out = (float*)d_out;

  if (ws_size >= (size_t)WS_USHORTS * sizeof(unsigned short)) {
    unsigned short* wsB = (unsigned short*)d_ws;
    prep_weights<<<144, 256, 0, stream>>>(Wk_enc, Wr_enc, Wk_dec, Wr_dec, wsB);
    ed_mfma<<<256, NTHR, 0, stream>>>(a, b, W_combine, b_combine, W_first, b_first,
                                      bias_enc, bias_dec, W_out, b_out, wsB, out);
  } else {
    ed_fallback<<<256, FNTHR, 0, stream>>>(a, b, W_combine, b_combine, W_first, b_first,
                                           Wk_enc, Wr_enc, bias_enc, Wk_dec, Wr_dec,
                                           bias_dec, W_out, b_out, out);
  }
}